// Round 19
// baseline (215.200 us; speedup 1.0000x reference)
//
#include <hip/hip_runtime.h>
#include <cstdint>
#include <cstddef>

#define NSEG 32769      // N_NODES + 1 (row 0 is the zero row)
#define NNODES 32768
#define NE 262144
#define PSZ ((size_t)NSEG * 64)   // one tf plane

using f4 = float4;
typedef __attribute__((ext_vector_type(8))) short bf16x8;
typedef __attribute__((ext_vector_type(4))) float f32x4;

// ---------------- static device scratch (load-time zero-initialized) ----------------
__device__ ushort g_tfp[4 * PSZ];                 // planes 0..2 out cols (iter2), plane 3 h_orig
__device__ uint   g_pkA[PSZ];                     // (out0 | h)  after iter0
__device__ uint   g_pk01[PSZ];                    // (out0 | out1) after iter1 gemm
__device__ ushort g_msumh[(size_t)NSEG * 192];    // bf16 row-major (K width 192)
__device__ float  g_q[NSEG];
__device__ float  g_p0[3][NSEG];
__device__ float  g_p1[3][NSEG];
__device__ float  g_w2[3][256];                   // w2 = W @ a2 in [0,d); c = a2.b at [255]
__device__ float  g_wq10[10];                     // W_dist @ w2_0
__device__ float  g_cq;                           // b_dist.w2_0 + a0.b0
__device__ float  g_wc[640];                      // Wc = W_dist @ fc_W0 (10x64)
__device__ float  g_bcc[64];                      // b_dist @ fc_W0 + fc_b0
__device__ ushort g_wbB[16384];                   // fc_W1 in MFMA B-frag layout
__device__ ushort g_wbC[36864];                   // fc_W2 in MFMA B-frag layout
__device__ f4     g_rec[(size_t)NE * 4];          // per-edge: {x0..3}{x4..7}{x8,x9,lb0,_}{pe1,pe2,g1,g2}
__device__ int    g_counts[NSEG];                 // zeroed by k_mid (prev call) / load
__device__ int    g_excl[NSEG];
__device__ int    g_bsum[1024];
__device__ int    g_rowptr[NSEG + 1];
__device__ int    g_cur[NSEG];                    // zeroed by k_mid (prev call) / load
__device__ int    g_csr[NE];
__device__ int    g_g1s[NE];                      // gather indices, CSR-sorted
__device__ int    g_g2s[NE];
__device__ float  g_pe1[NE];                      // p0[1][s0]+p1[1][s1], CSR-sorted
__device__ float  g_pe2[NE];                      // p0[2][s0]+p1[2][s1], CSR-sorted
__device__ int    g_bc[128];                      // zeroed by k_gemmB (prev call) / load
__device__ int    g_bcur[128];
__device__ int    g_sorder[NSEG];

#define WREDUCE(x) { x += __shfl_xor(x, 32); x += __shfl_xor(x, 16); \
                     x += __shfl_xor(x, 8);  x += __shfl_xor(x, 4);  \
                     x += __shfl_xor(x, 2);  x += __shfl_xor(x, 1); }
#define WREDMAX(x) { x = fmaxf(x, __shfl_xor(x, 32)); x = fmaxf(x, __shfl_xor(x, 16)); \
                     x = fmaxf(x, __shfl_xor(x, 8));  x = fmaxf(x, __shfl_xor(x, 4));  \
                     x = fmaxf(x, __shfl_xor(x, 2));  x = fmaxf(x, __shfl_xor(x, 1)); }
#define GREDUCE(x) { x += __shfl_xor(x, 8); x += __shfl_xor(x, 4); \
                     x += __shfl_xor(x, 2); x += __shfl_xor(x, 1); }
#define GREDMAX(x) { x = fmaxf(x, __shfl_xor(x, 8)); x = fmaxf(x, __shfl_xor(x, 4)); \
                     x = fmaxf(x, __shfl_xor(x, 2)); x = fmaxf(x, __shfl_xor(x, 1)); }

__device__ __forceinline__ ushort f2bf(float x) {
    uint u = __float_as_uint(x);
    u += 0x7FFF + ((u >> 16) & 1);
    return (ushort)(u >> 16);
}
__device__ __forceinline__ float bfs(ushort u) { return __uint_as_float(((uint)u) << 16); }
__device__ __forceinline__ float bflo(uint u) { return __uint_as_float(u << 16); }
__device__ __forceinline__ float bfhi(uint u) { return __uint_as_float(u & 0xFFFF0000u); }

// ===== k_front: emb 64-rows/block (0..512) | prep (513..517) | fragB (518) |
//                fragC (519..520) | hist (521..1544) =====
__global__ __launch_bounds__(256) void k_front(
    const float* __restrict__ node_feats, const float* __restrict__ We,
    const float* __restrict__ be,
    const float* __restrict__ a0, const float* __restrict__ a1, const float* __restrict__ a2,
    const float* __restrict__ W0, const float* __restrict__ W1, const float* __restrict__ W2,
    const float* __restrict__ b0, const float* __restrict__ b1, const float* __restrict__ b2,
    const float* __restrict__ Wd, const float* __restrict__ bd,
    const int* __restrict__ bscope) {
    int tid = threadIdx.x;
    if (blockIdx.x < 513) {
        __shared__ float Ws[576];
        __shared__ float As6[6][68];
        __shared__ float fsAll[576];
        __shared__ float hsAll[64][68];
        int r0 = blockIdx.x * 64;
        for (int i = tid; i < 576; i += 256) Ws[i] = We[i];
        for (int t = tid; t < 384; t += 256) {
            int vec = t >> 6, j = t & 63;
            const float* Av = (vec >> 1) == 0 ? a0 : ((vec >> 1) == 1 ? a1 : a2);
            As6[vec][j] = Av[((vec & 1) << 6) + j];
        }
        for (int t = tid; t < 576; t += 256) {
            int row = r0 + t / 9;
            float v = 0.f;
            if (row >= 1 && row <= NNODES) v = node_feats[(size_t)(row - 1) * 9 + (t % 9)];
            fsAll[t] = v;
        }
        __syncthreads();
        int j = tid & 63;
        float bj = be[j];
#pragma unroll 4
        for (int p = 0; p < 16; p++) {
            int lr = p * 4 + (tid >> 6);
            int row = r0 + lr;
            float acc = bj;
#pragma unroll
            for (int k = 0; k < 9; k++) acc += fsAll[lr * 9 + k] * Ws[k * 64 + j];
            float v = (row == 0 || row >= NSEG) ? 0.f : acc;
            if (row < NSEG) g_tfp[3 * PSZ + (size_t)row * 64 + j] = f2bf(v);
            hsAll[lr][j] = v;
        }
        __syncthreads();
#pragma unroll
        for (int i = 0; i < 12; i++) {
            int task = i * 256 + tid;
            int d = task >> 3, g = tid & 7;
            int lr = d / 6, vec = d % 6;
            float s = 0.f;
#pragma unroll
            for (int jj = 0; jj < 8; jj++)
                s += hsAll[lr][g * 8 + jj] * As6[vec][g * 8 + jj];
            s += __shfl_xor(s, 1); s += __shfl_xor(s, 2); s += __shfl_xor(s, 4);
            int prow = r0 + lr;
            if (g == 0 && prow < NSEG) {
                int iv = vec >> 1;
                if ((vec & 1) == 0) g_p0[iv][prow] = s;
                else                g_p1[iv][prow] = s;
            }
        }
    } else if (blockIdx.x < 518) {
        int pb = blockIdx.x - 513;
        int k = tid;
        if (pb < 3) {
            int it = pb;
            const float* W = it == 0 ? W0 : (it == 1 ? W1 : W2);
            const float* a = it == 0 ? a0 : (it == 1 ? a1 : a2);
            const float* bias = it == 0 ? b0 : (it == 1 ? b1 : b2);
            int d = 64 * (it + 1);
            if (k < d) {
                float s = 0.f;
                for (int jj = 0; jj < d; jj++) s += W[(size_t)k * d + jj] * a[128 + jj];
                g_w2[it][k] = s;
            } else if (k == 255) {
                float c = 0.f;
                for (int jj = 0; jj < d; jj++) c += a[128 + jj] * bias[jj];
                g_w2[it][255] = c;
            }
        } else if (pb == 3) {
            __shared__ float w2s[64];
            if (k < 64) {
                float s = 0.f;
                for (int jj = 0; jj < 64; jj++) s += W0[(size_t)k * 64 + jj] * a0[128 + jj];
                w2s[k] = s;
            }
            __syncthreads();
            if (k < 10) {
                float s = 0.f;
                for (int jj = 0; jj < 64; jj++) s += Wd[(size_t)k * 64 + jj] * w2s[jj];
                g_wq10[k] = s;
            } else if (k == 64) {
                float s = 0.f, c = 0.f;
                for (int jj = 0; jj < 64; jj++) { s += bd[jj] * w2s[jj]; c += a0[128 + jj] * b0[jj]; }
                g_cq = s + c;
            }
        } else {
            for (int t = k; t < 640; t += 256) {
                int kk = t >> 6, jj = t & 63;
                float s = 0.f;
                for (int m = 0; m < 64; m++) s += Wd[kk * 64 + m] * W0[(size_t)m * 64 + jj];
                g_wc[t] = s;
            }
            if (k < 64) {
                float s = b0[k];
                for (int m = 0; m < 64; m++) s += bd[m] * W0[(size_t)m * 64 + k];
                g_bcc[k] = s;
            }
        }
    } else if (blockIdx.x == 518) {
        for (int t = tid; t < 2048; t += 256) {
            int nt = t >> 8, ks = (t >> 6) & 3, l = t & 63;
            int n = nt * 16 + (l & 15);
            int kb = ks * 32 + ((l >> 4) << 3);
            ushort* dst = &g_wbB[(size_t)t * 8];
#pragma unroll
            for (int i = 0; i < 8; i++)
                dst[i] = f2bf(W1[(size_t)(kb + i) * 128 + n]);
        }
    } else if (blockIdx.x <= 520) {
        int half = blockIdx.x - 519;
        for (int t = tid; t < 2304; t += 256) {
            int nt = half * 6 + t / 384;
            int rem = t % 384;
            int ks = rem >> 6, l = rem & 63;
            int n = nt * 16 + (l & 15);
            int kb = ks * 32 + ((l >> 4) << 3);
            ushort* dst = &g_wbC[((size_t)(nt * 6 + ks) * 64 + l) * 8];
#pragma unroll
            for (int i = 0; i < 8; i++)
                dst[i] = f2bf(W2[(size_t)(kb + i) * 192 + n]);
        }
    } else {
        int e = (blockIdx.x - 521) * 256 + tid;
        if (e < NE) atomicAdd(&g_counts[bscope[e]], 1);
    }
}

// ---------------- scans ----------------
__global__ void k_scan1() {
    __shared__ int s[256];
    int t = threadIdx.x, i = blockIdx.x * 256 + t;
    int v = (i < NSEG) ? g_counts[i] : 0;
    s[t] = v; __syncthreads();
    for (int off = 1; off < 256; off <<= 1) {
        int tmp = (t >= off) ? s[t - off] : 0;
        __syncthreads();
        s[t] += tmp;
        __syncthreads();
    }
    if (i < NSEG) g_excl[i] = s[t] - v;
    if (t == 255) g_bsum[blockIdx.x] = s[255];
}

__global__ void k_scan2(int nb) {
    __shared__ int s[256];
    int t = threadIdx.x;
    int v = (t < nb) ? g_bsum[t] : 0;
    s[t] = v; __syncthreads();
    for (int off = 1; off < 256; off <<= 1) {
        int tmp = (t >= off) ? s[t - off] : 0;
        __syncthreads();
        s[t] += tmp;
        __syncthreads();
    }
    if (t < nb) g_bsum[t] = s[t] - v;   // exclusive
}

__global__ void k_scan3() {
    __shared__ int lh[128];
    int t = threadIdx.x;
    if (t < 128) lh[t] = 0;
    __syncthreads();
    int i = blockIdx.x * 256 + t;
    if (i < NSEG) {
        g_rowptr[i] = g_excl[i] + g_bsum[i >> 8];
        int cnt = g_counts[i];
        atomicAdd(&lh[cnt > 127 ? 127 : cnt], 1);
    }
    if (i == NSEG) g_rowptr[NSEG] = NE;
    __syncthreads();
    if (t < 128 && lh[t]) atomicAdd(&g_bc[t], lh[t]);
}

// ---- scatter + per-edge 64B record build ----
__global__ __launch_bounds__(256) void k_scatter(const int* __restrict__ bs,
                                                 const float* __restrict__ fdg,
                                                 const float* __restrict__ rij,
                                                 const int* __restrict__ see,
                                                 const int* __restrict__ g1,
                                                 const int* __restrict__ g2) {
    __shared__ float wqs[10];
    if (threadIdx.x < 10) wqs[threadIdx.x] = g_wq10[threadIdx.x];
    __syncthreads();
    int e = blockIdx.x * 256 + threadIdx.x;
    if (e >= NE) return;
    int seg = bs[e];
    int pos = g_rowptr[seg] + atomicAdd(&g_cur[seg], 1);
    g_csr[pos] = e;
    float x[10];
#pragma unroll
    for (int k = 0; k < 9; k++) x[k] = fdg[(size_t)e * 9 + k];
    x[9] = rij[e];
    int s0 = see[2 * (size_t)e], s1 = see[2 * (size_t)e + 1];
    float q = g_cq;
#pragma unroll
    for (int k = 0; k < 10; k++) q += x[k] * wqs[k];
    float lb0 = q + g_p0[0][s0] + g_p1[0][s1];
    float pe1 = g_p0[1][s0] + g_p1[1][s1];
    float pe2 = g_p0[2][s0] + g_p1[2][s1];
    size_t rb = (size_t)e * 4;
    g_rec[rb + 0] = make_float4(x[0], x[1], x[2], x[3]);
    g_rec[rb + 1] = make_float4(x[4], x[5], x[6], x[7]);
    g_rec[rb + 2] = make_float4(x[8], x[9], lb0, 0.f);
    g_rec[rb + 3] = make_float4(pe1, pe2, __int_as_float(g1[e]), __int_as_float(g2[e]));
}

// ===== k_mid: bscatter (0..128, + counts/cur cleanup) | sortidx (129..1152) |
//              attend0 unsorted (1153..9345) =====
__global__ __launch_bounds__(256) void k_mid() {
    int tid = threadIdx.x;
    if (blockIdx.x < 129) {
        __shared__ int sc[128];
        __shared__ int lh[128];
        __shared__ int lbase[128];
        if (tid < 128) { sc[tid] = g_bc[tid]; lh[tid] = 0; }
        __syncthreads();
        for (int off = 1; off < 128; off <<= 1) {
            int tmp = (tid >= off && tid < 128) ? sc[tid - off] : 0;
            __syncthreads();
            if (tid < 128) sc[tid] += tmp;
            __syncthreads();
        }
        int seg = blockIdx.x * 256 + tid;
        int bin = 0, lpos = 0;
        bool valid = seg < NSEG;
        if (valid) {
            int cnt = g_rowptr[seg + 1] - g_rowptr[seg];
            bin = cnt > 127 ? 127 : cnt;
            lpos = atomicAdd(&lh[bin], 1);
        }
        __syncthreads();
        if (tid < 128 && lh[tid] > 0)
            lbase[tid] = atomicAdd(&g_bcur[tid], lh[tid]);
        __syncthreads();
        if (valid) {
            int bstart = sc[bin] - g_bc[bin];
            g_sorder[bstart + lbase[bin] + lpos] = seg;
            g_counts[seg] = 0;
            g_cur[seg] = 0;
        }
    } else if (blockIdx.x < 1153) {
        int pos = (blockIdx.x - 129) * 256 + tid;
        if (pos >= NE) return;
        int e = g_csr[pos];
        f4 d = g_rec[(size_t)e * 4 + 3];
        g_pe1[pos] = d.x;
        g_pe2[pos] = d.y;
        g_g1s[pos] = __float_as_int(d.z);
        g_g2s[pos] = __float_as_int(d.w);
    } else {
        __shared__ float Wcs[640];
        __shared__ float bcs[64];
        for (int i = tid; i < 640; i += 256) Wcs[i] = g_wc[i];
        if (tid < 64) bcs[tid] = g_bcc[tid];
        __syncthreads();
        int lane = tid & 63;
        int seg = (blockIdx.x - 1153) * 4 + (tid >> 6);
        if (seg >= NSEG) return;
        int beg = g_rowptr[seg], end = g_rowptr[seg + 1];
        int cnt = end - beg;
        float y[10];
#pragma unroll
        for (int k = 0; k < 10; k++) y[k] = 0.f;

        if (cnt > 0 && cnt <= 64) {
            float l = -1e30f;
            float x[10];
#pragma unroll
            for (int k = 0; k < 10; k++) x[k] = 0.f;
            if (lane < cnt) {
                int e = g_csr[beg + lane];
                size_t rb = (size_t)e * 4;
                f4 r0 = g_rec[rb + 0];
                f4 r1 = g_rec[rb + 1];
                f4 r2 = g_rec[rb + 2];
                x[0] = r0.x; x[1] = r0.y; x[2] = r0.z; x[3] = r0.w;
                x[4] = r1.x; x[5] = r1.y; x[6] = r1.z; x[7] = r1.w;
                x[8] = r2.x; x[9] = r2.y;
                l = r2.z;
                l = l > 0.f ? l : 0.2f * l;
            }
            float m = l;
            WREDMAX(m);
            float ex = (lane < cnt) ? __expf(l - m) : 0.f;
            float den = ex;
            WREDUCE(den);
            float w = ex / den;
#pragma unroll
            for (int k = 0; k < 10; k++) {
                float s = w * x[k];
                WREDUCE(s);
                y[k] = s;
            }
        } else if (cnt > 64) {
            float m = -1e30f;
            for (int t = beg + lane; t < end; t += 64) {
                int e = g_csr[t];
                float l = g_rec[(size_t)e * 4 + 2].z;
                l = l > 0.f ? l : 0.2f * l;
                m = fmaxf(m, l);
            }
            WREDMAX(m);
            float den = 0.f;
            for (int t = beg + lane; t < end; t += 64) {
                int e = g_csr[t];
                float l = g_rec[(size_t)e * 4 + 2].z;
                l = l > 0.f ? l : 0.2f * l;
                den += __expf(l - m);
            }
            WREDUCE(den);
            float rden = 1.f / den;
            float part[10];
#pragma unroll
            for (int k = 0; k < 10; k++) part[k] = 0.f;
            for (int t = beg + lane; t < end; t += 64) {
                int e = g_csr[t];
                size_t rb = (size_t)e * 4;
                f4 r0 = g_rec[rb + 0];
                f4 r1 = g_rec[rb + 1];
                f4 r2 = g_rec[rb + 2];
                float l = r2.z;
                l = l > 0.f ? l : 0.2f * l;
                float w = __expf(l - m) * rden;
                part[0] += w * r0.x; part[1] += w * r0.y; part[2] += w * r0.z; part[3] += w * r0.w;
                part[4] += w * r1.x; part[5] += w * r1.y; part[6] += w * r1.z; part[7] += w * r1.w;
                part[8] += w * r2.x; part[9] += w * r2.y;
            }
#pragma unroll
            for (int k = 0; k < 10; k++) {
                WREDUCE(part[k]);
                y[k] = part[k];
            }
        }
        float o = bcs[lane];
#pragma unroll
        for (int k = 0; k < 10; k++) o += y[k] * Wcs[k * 64 + lane];
        if (cnt == 0) o = 0.f;
        o = o > 0.f ? o : (__expf(o) - 1.f);
        ushort h = g_tfp[3 * PSZ + (size_t)seg * 64 + lane];
        g_pkA[(size_t)seg * 64 + lane] = (uint)f2bf(o) | ((uint)h << 16);
        float qp = o * g_w2[1][lane] + bfs(h) * g_w2[1][64 + lane];
        WREDUCE(qp);
        if (lane == 0) g_q[seg] = qp + g_w2[1][255];
    }
}

// -------- full-wave per-segment attend (fallback for cnt > 16) --------
template <int NCM>
__device__ __forceinline__ void attend_full(int seg, const float* __restrict__ pe, int lane) {
    int beg = g_rowptr[seg], end = g_rowptr[seg + 1];
    int cnt = end - beg;
    float acc[NCM];
#pragma unroll
    for (int c = 0; c < NCM; c++) acc[c] = 0.f;

    if (cnt > 0 && cnt <= 64) {
        float l = -1e30f;
        int i1 = 0, i2 = 0;
        if (lane < cnt) {
            i1 = g_g1s[beg + lane]; i2 = g_g2s[beg + lane];
            l = 0.5f * (g_q[i1] + g_q[i2]) + pe[beg + lane];
            l = l > 0.f ? l : 0.2f * l;
        }
        float m = l;
        WREDMAX(m);
        float ex = (lane < cnt) ? __expf(l - m) : 0.f;
        float den = ex;
        WREDUCE(den);
        float w = ex / den;
        for (int t0 = 0; t0 < cnt; t0 += 8) {
            float wt[8]; int a1[8], a2[8];
#pragma unroll
            for (int u = 0; u < 8; u++) {
                int su = t0 + u; su = su > 63 ? 63 : su;
                wt[u] = __shfl(w, su);
                a1[u] = __shfl(i1, su);
                a2[u] = __shfl(i2, su);
            }
            if (NCM == 2) {
                uint ua[8], ub[8];
#pragma unroll
                for (int u = 0; u < 8; u++) {
                    ua[u] = g_pkA[(size_t)a1[u] * 64 + lane];
                    ub[u] = g_pkA[(size_t)a2[u] * 64 + lane];
                }
#pragma unroll
                for (int u = 0; u < 8; u++) {
                    float wh = 0.5f * wt[u];
                    acc[0] += wh * (bflo(ua[u]) + bflo(ub[u]));
                    acc[1] += wh * (bfhi(ua[u]) + bfhi(ub[u]));
                }
            } else {
                uint ua[8], ub[8];
                ushort ha[8], hb[8];
#pragma unroll
                for (int u = 0; u < 8; u++) {
                    size_t b1 = (size_t)a1[u] * 64 + lane, b2 = (size_t)a2[u] * 64 + lane;
                    ua[u] = g_pk01[b1]; ub[u] = g_pk01[b2];
                    ha[u] = g_tfp[3 * PSZ + b1]; hb[u] = g_tfp[3 * PSZ + b2];
                }
#pragma unroll
                for (int u = 0; u < 8; u++) {
                    float wh = 0.5f * wt[u];
                    acc[0] += wh * (bflo(ua[u]) + bflo(ub[u]));
                    acc[1] += wh * (bfhi(ua[u]) + bfhi(ub[u]));
                    acc[2] += wh * (bfs(ha[u]) + bfs(hb[u]));
                }
            }
        }
    } else if (cnt > 64) {
        float m = -1e30f;
        for (int t = beg + lane; t < end; t += 64) {
            float l = 0.5f * (g_q[g_g1s[t]] + g_q[g_g2s[t]]) + pe[t];
            l = l > 0.f ? l : 0.2f * l;
            m = fmaxf(m, l);
        }
        WREDMAX(m);
        float den = 0.f;
        for (int t = beg + lane; t < end; t += 64) {
            float l = 0.5f * (g_q[g_g1s[t]] + g_q[g_g2s[t]]) + pe[t];
            l = l > 0.f ? l : 0.2f * l;
            den += __expf(l - m);
        }
        WREDUCE(den);
        float rden = 1.f / den;
        for (int t = beg; t < end; t++) {
            float l = 0.5f * (g_q[g_g1s[t]] + g_q[g_g2s[t]]) + pe[t];
            l = l > 0.f ? l : 0.2f * l;
            float w = __expf(l - m) * rden;
            float wh = 0.5f * w;
            size_t b1 = (size_t)g_g1s[t] * 64 + lane, b2 = (size_t)g_g2s[t] * 64 + lane;
            if (NCM == 3) {
                uint ua = g_pk01[b1], ub = g_pk01[b2];
                acc[0] += wh * (bflo(ua) + bflo(ub));
                acc[1] += wh * (bfhi(ua) + bfhi(ub));
                acc[2] += wh * (bfs(g_tfp[3 * PSZ + b1]) + bfs(g_tfp[3 * PSZ + b2]));
            } else {
                uint ua = g_pkA[b1], ub = g_pkA[b2];
                acc[0] += wh * (bflo(ua) + bflo(ub));
                acc[1] += wh * (bfhi(ua) + bfhi(ub));
            }
        }
    }
#pragma unroll
    for (int c = 0; c < NCM; c++)
        g_msumh[(size_t)seg * 192 + lane + 64 * c] = f2bf(acc[c]);
}

// -------- attend iters 1/2: 16-lane groups, 4 segments/wave (size-sorted) --------
template <int NCM>
__global__ __launch_bounds__(256) void k_attendG() {
    const float* __restrict__ pe = (NCM == 2) ? g_pe1 : g_pe2;
    int tid = threadIdx.x;
    int lane = tid & 63;
    int sidx0 = (blockIdx.x * 4 + (tid >> 6)) * 4;   // 4 segs per wave
    if (sidx0 >= NSEG) return;
    int g = lane >> 4, ln = lane & 15;
    int sidx = sidx0 + g;
    bool gvalid = sidx < NSEG;
    int seg = gvalid ? g_sorder[sidx] : 0;
    int beg = gvalid ? g_rowptr[seg] : 0;
    int end = gvalid ? g_rowptr[seg + 1] : 0;
    int cnt = end - beg;
    int mx = cnt;
    mx = max(mx, __shfl_xor(mx, 16));
    mx = max(mx, __shfl_xor(mx, 32));

    if (mx <= 16) {
        // grouped path: lane owns cols 4ln..4ln+3 of its group's segment
        float l = -1e30f;
        int i1 = 0, i2 = 0;
        if (gvalid && ln < cnt) {
            i1 = g_g1s[beg + ln]; i2 = g_g2s[beg + ln];
            l = 0.5f * (g_q[i1] + g_q[i2]) + pe[beg + ln];
            l = l > 0.f ? l : 0.2f * l;
        }
        float m = l;
        GREDMAX(m);
        float ex = (gvalid && ln < cnt) ? __expf(l - m) : 0.f;
        float den = ex;
        GREDUCE(den);
        float w = ex / den;    // 0 for ln >= cnt (cnt>0); unused if cnt==0
        float acc[NCM][4];
#pragma unroll
        for (int c = 0; c < NCM; c++)
#pragma unroll
            for (int j = 0; j < 4; j++) acc[c][j] = 0.f;
        int gbase = lane & 48;   // g*16
        for (int t0 = 0; t0 < cnt; t0 += 4) {
            float wt[4]; int a1[4], a2[4];
#pragma unroll
            for (int u = 0; u < 4; u++) {
                int su = t0 + u; su = su > 15 ? 15 : su;
                wt[u] = __shfl(w, gbase + su);
                a1[u] = __shfl(i1, gbase + su);
                a2[u] = __shfl(i2, gbase + su);
            }
            if (NCM == 2) {
                uint4 pa[4], pb[4];
#pragma unroll
                for (int u = 0; u < 4; u++) {
                    pa[u] = *(const uint4*)&g_pkA[(size_t)a1[u] * 64 + ln * 4];
                    pb[u] = *(const uint4*)&g_pkA[(size_t)a2[u] * 64 + ln * 4];
                }
#pragma unroll
                for (int u = 0; u < 4; u++) {
                    float wh = 0.5f * wt[u];
                    uint ua[4] = {pa[u].x, pa[u].y, pa[u].z, pa[u].w};
                    uint ub[4] = {pb[u].x, pb[u].y, pb[u].z, pb[u].w};
#pragma unroll
                    for (int j = 0; j < 4; j++) {
                        acc[0][j] += wh * (bflo(ua[j]) + bflo(ub[j]));
                        acc[1][j] += wh * (bfhi(ua[j]) + bfhi(ub[j]));
                    }
                }
            } else {
                uint4 pa[4], pb[4];
                ushort4 ha[4], hb[4];
#pragma unroll
                for (int u = 0; u < 4; u++) {
                    size_t b1 = (size_t)a1[u] * 64 + ln * 4, b2 = (size_t)a2[u] * 64 + ln * 4;
                    pa[u] = *(const uint4*)&g_pk01[b1];
                    pb[u] = *(const uint4*)&g_pk01[b2];
                    ha[u] = *(const ushort4*)&g_tfp[3 * PSZ + b1];
                    hb[u] = *(const ushort4*)&g_tfp[3 * PSZ + b2];
                }
#pragma unroll
                for (int u = 0; u < 4; u++) {
                    float wh = 0.5f * wt[u];
                    uint ua[4] = {pa[u].x, pa[u].y, pa[u].z, pa[u].w};
                    uint ub[4] = {pb[u].x, pb[u].y, pb[u].z, pb[u].w};
                    ushort va[4] = {ha[u].x, ha[u].y, ha[u].z, ha[u].w};
                    ushort vb[4] = {hb[u].x, hb[u].y, hb[u].z, hb[u].w};
#pragma unroll
                    for (int j = 0; j < 4; j++) {
                        acc[0][j] += wh * (bflo(ua[j]) + bflo(ub[j]));
                        acc[1][j] += wh * (bfhi(ua[j]) + bfhi(ub[j]));
                        acc[2][j] += wh * (bfs(va[j]) + bfs(vb[j]));
                    }
                }
            }
        }
        if (gvalid) {
#pragma unroll
            for (int c = 0; c < NCM; c++) {
                ushort4 o;
                o.x = f2bf(acc[c][0]); o.y = f2bf(acc[c][1]);
                o.z = f2bf(acc[c][2]); o.w = f2bf(acc[c][3]);
                *(ushort4*)&g_msumh[(size_t)seg * 192 + c * 64 + ln * 4] = o;
            }
        }
    } else {
        // fallback: full wave per segment, 4 segments sequentially
        for (int ii = 0; ii < 4; ii++) {
            int si = sidx0 + ii;
            if (si < NSEG) attend_full<NCM>(g_sorder[si], pe, lane);
        }
    }
}

// ----- iter1 GEMM (MFMA): 64 rows/block, 4 waves x (16 rows x 128 cols); K=128 -----
__global__ __launch_bounds__(256) void k_gemmB(const float* __restrict__ bias) {
    int tid = threadIdx.x;
    if (blockIdx.x == 0 && tid < 128) { g_bc[tid] = 0; g_bcur[tid] = 0; }
    int w = tid >> 6, l = tid & 63;
    int lm = l & 15, lk = l >> 4;
    int r0 = blockIdx.x * 64 + w * 16;
    int arow = r0 + lm;
    size_t abase = (size_t)(arow < NSEG ? arow : 0) * 192;
    f32x4 acc[8];
#pragma unroll
    for (int nt = 0; nt < 8; nt++) acc[nt] = (f32x4){0.f, 0.f, 0.f, 0.f};
#pragma unroll
    for (int ks = 0; ks < 4; ks++) {
        bf16x8 af = *(const bf16x8*)&g_msumh[abase + ks * 32 + lk * 8];
#pragma unroll
        for (int nt = 0; nt < 8; nt++) {
            bf16x8 bf = *(const bf16x8*)&g_wbB[((size_t)(nt * 4 + ks) * 64 + l) * 8];
            acc[nt] = __builtin_amdgcn_mfma_f32_16x16x32_bf16(af, bf, acc[nt], 0, 0, 0);
        }
    }
#pragma unroll
    for (int j = 0; j < 4; j++) {
        int row = r0 + lk * 4 + j;
        bool valid = row < NSEG;
        int rr = valid ? row : 0;
        bool nonempty = valid && (g_rowptr[row + 1] > g_rowptr[row]);
        float qp = 0.f;
#pragma unroll
        for (int nt = 0; nt < 4; nt++) {
            int c = nt * 16 + lm;
            float vl = acc[nt][j] + bias[c];
            float vh = acc[nt + 4][j] + bias[64 + c];
            if (!nonempty) { vl = 0.f; vh = 0.f; }
            vl = vl > 0.f ? vl : (__expf(vl) - 1.f);
            vh = vh > 0.f ? vh : (__expf(vh) - 1.f);
            float hc = bfs(g_tfp[3 * PSZ + (size_t)rr * 64 + c]);
            if (valid) g_pk01[(size_t)row * 64 + c] = (uint)f2bf(vl) | ((uint)f2bf(vh) << 16);
            qp += vl * g_w2[2][c] + vh * g_w2[2][64 + c] + hc * g_w2[2][128 + c];
        }
        qp += __shfl_xor(qp, 1); qp += __shfl_xor(qp, 2);
        qp += __shfl_xor(qp, 4); qp += __shfl_xor(qp, 8);
        if (valid && lm == 0) g_q[row] = qp + g_w2[2][255];
    }
}

// ----- iter2 GEMM (MFMA): 64 rows/block, 4 waves x (16 rows x 192 cols); K=192 -----
__global__ __launch_bounds__(256) void k_gemmC(const float* __restrict__ bias) {
    int tid = threadIdx.x;
    int w = tid >> 6, l = tid & 63;
    int lm = l & 15, lk = l >> 4;
    int r0 = blockIdx.x * 64 + w * 16;
    int arow = r0 + lm;
    size_t abase = (size_t)(arow < NSEG ? arow : 0) * 192;
    f32x4 acc[12];
#pragma unroll
    for (int nt = 0; nt < 12; nt++) acc[nt] = (f32x4){0.f, 0.f, 0.f, 0.f};
#pragma unroll
    for (int ks = 0; ks < 6; ks++) {
        bf16x8 af = *(const bf16x8*)&g_msumh[abase + ks * 32 + lk * 8];
#pragma unroll
        for (int nt = 0; nt < 12; nt++) {
            bf16x8 bf = *(const bf16x8*)&g_wbC[((size_t)(nt * 6 + ks) * 64 + l) * 8];
            acc[nt] = __builtin_amdgcn_mfma_f32_16x16x32_bf16(af, bf, acc[nt], 0, 0, 0);
        }
    }
#pragma unroll
    for (int j = 0; j < 4; j++) {
        int row = r0 + lk * 4 + j;
        if (row >= NSEG) continue;
        bool nonempty = g_rowptr[row + 1] > g_rowptr[row];
#pragma unroll
        for (int nt = 0; nt < 12; nt++) {
            int col = nt * 16 + lm;
            float v = acc[nt][j] + bias[col];
            if (!nonempty) v = 0.f;
            v = v > 0.f ? v : (__expf(v) - 1.f);
            int plane = nt >> 2, c = col & 63;
            g_tfp[(size_t)plane * PSZ + (size_t)row * 64 + c] = f2bf(v);
        }
    }
}

// ---------------- final: per-molecule gather-sum ----------------
__global__ void k_final(const int* __restrict__ lscope, float* __restrict__ out) {
    __shared__ int idx[32];
    __shared__ float sm[4][256];
    int m = blockIdx.x, tid = threadIdx.x, w = tid >> 6, lane = tid & 63;
    if (tid < 32) idx[tid] = lscope[m * 32 + tid];
    __syncthreads();
    float a0 = 0.f, a1 = 0.f, a2 = 0.f, a3 = 0.f;
#pragma unroll
    for (int j = w * 8; j < w * 8 + 8; j++) {
        size_t base = (size_t)idx[j] * 64 + lane;
        a0 += bfs(g_tfp[base]);
        a1 += bfs(g_tfp[PSZ + base]);
        a2 += bfs(g_tfp[2 * PSZ + base]);
        a3 += bfs(g_tfp[3 * PSZ + base]);
    }
    sm[w][lane] = a0; sm[w][64 + lane] = a1; sm[w][128 + lane] = a2; sm[w][192 + lane] = a3;
    __syncthreads();
    out[(size_t)m * 256 + tid] = sm[0][tid] + sm[1][tid] + sm[2][tid] + sm[3][tid];
}

extern "C" void kernel_launch(void* const* d_in, const int* in_sizes, int n_in,
                              void* d_out, int out_size, void* d_ws, size_t ws_size,
                              hipStream_t stream) {
    const float* node_feats = (const float*)d_in[0];
    const float* fdg        = (const float*)d_in[1];
    const float* rij        = (const float*)d_in[2];
    const int*   see        = (const int*)d_in[3];
    const int*   b_scope    = (const int*)d_in[4];
    const int*   scope_up   = (const int*)d_in[5];
    const int*   scope_lig  = (const int*)d_in[6];
    const int*   l_scope    = (const int*)d_in[7];
    const float* W_emb      = (const float*)d_in[8];
    const float* b_emb      = (const float*)d_in[9];
    const float* W_dist     = (const float*)d_in[10];
    const float* b_dist     = (const float*)d_in[11];
    const float* fc_W[3]   = {(const float*)d_in[12], (const float*)d_in[15], (const float*)d_in[18]};
    const float* fc_b[3]   = {(const float*)d_in[13], (const float*)d_in[16], (const float*)d_in[19]};
    const float* attn_a[3] = {(const float*)d_in[14], (const float*)d_in[17], (const float*)d_in[20]};

    k_front<<<1545, 256, 0, stream>>>(node_feats, W_emb, b_emb,
                                      attn_a[0], attn_a[1], attn_a[2],
                                      fc_W[0], fc_W[1], fc_W[2],
                                      fc_b[0], fc_b[1], fc_b[2],
                                      W_dist, b_dist, b_scope);
    k_scan1<<<129, 256, 0, stream>>>();
    k_scan2<<<1, 256, 0, stream>>>(129);
    k_scan3<<<129, 256, 0, stream>>>();
    k_scatter<<<NE / 256, 256, 0, stream>>>(b_scope, fdg, rij, see, scope_lig, scope_up);
    k_mid<<<9346, 256, 0, stream>>>();

    // iter 1  (16 segs per block)
    k_attendG<2><<<2049, 256, 0, stream>>>();
    k_gemmB<<<513, 256, 0, stream>>>(fc_b[1]);
    // iter 2
    k_attendG<3><<<2049, 256, 0, stream>>>();
    k_gemmC<<<513, 256, 0, stream>>>(fc_b[2]);

    k_final<<<2048, 256, 0, stream>>>(l_scope, (float*)d_out);
}

// Round 20
// 203.570 us; speedup vs baseline: 1.0571x; 1.0571x over previous
//
#include <hip/hip_runtime.h>
#include <cstdint>
#include <cstddef>

#define NSEG 32769      // N_NODES + 1 (row 0 is the zero row)
#define NNODES 32768
#define NE 262144
#define PSZ ((size_t)NSEG * 64)   // one tf plane

using f4 = float4;
typedef __attribute__((ext_vector_type(8))) short bf16x8;
typedef __attribute__((ext_vector_type(4))) float f32x4;

// ---------------- static device scratch (load-time zero-initialized) ----------------
__device__ ushort g_tfp[4 * PSZ];                 // planes 0..2 out cols (iter2), plane 3 h_orig
__device__ uint   g_pkA[PSZ];                     // (out0 | h)  after iter0
__device__ uint   g_pk01[PSZ];                    // (out0 | out1) after iter1 gemm
__device__ ushort g_msumh[(size_t)NSEG * 192];    // bf16 row-major (K width 192)
__device__ float  g_q[NSEG];
__device__ float  g_p0[3][NSEG];
__device__ float  g_p1[3][NSEG];
__device__ float  g_w2[3][256];                   // w2 = W @ a2 in [0,d); c = a2.b at [255]
__device__ float  g_wq10[10];                     // W_dist @ w2_0
__device__ float  g_cq;                           // b_dist.w2_0 + a0.b0
__device__ float  g_wc[640];                      // Wc = W_dist @ fc_W0 (10x64)
__device__ float  g_bcc[64];                      // b_dist @ fc_W0 + fc_b0
__device__ ushort g_wbB[16384];                   // fc_W1 in MFMA B-frag layout
__device__ ushort g_wbC[36864];                   // fc_W2 in MFMA B-frag layout
__device__ f4     g_rec[(size_t)NE * 4];          // per-edge: {x0..3}{x4..7}{x8,x9,lb0,_}{pe1,pe2,g1,g2}
__device__ int    g_counts[NSEG];                 // zeroed by k_mid (prev call) / load
__device__ int    g_excl[NSEG];
__device__ int    g_bsum[1024];
__device__ int    g_rowptr[NSEG + 1];
__device__ int    g_cur[NSEG];                    // zeroed by k_mid (prev call) / load
__device__ int    g_csr[NE];
__device__ int    g_g1s[NE];                      // gather indices, CSR-sorted
__device__ int    g_g2s[NE];
__device__ float  g_pe1[NE];                      // p0[1][s0]+p1[1][s1], CSR-sorted
__device__ float  g_pe2[NE];                      // p0[2][s0]+p1[2][s1], CSR-sorted
__device__ int    g_bc[128];                      // zeroed by k_gemmB (prev call) / load
__device__ int    g_bcur[128];
__device__ int    g_sorder[NSEG];

#define WREDUCE(x) { x += __shfl_xor(x, 32); x += __shfl_xor(x, 16); \
                     x += __shfl_xor(x, 8);  x += __shfl_xor(x, 4);  \
                     x += __shfl_xor(x, 2);  x += __shfl_xor(x, 1); }
#define WREDMAX(x) { x = fmaxf(x, __shfl_xor(x, 32)); x = fmaxf(x, __shfl_xor(x, 16)); \
                     x = fmaxf(x, __shfl_xor(x, 8));  x = fmaxf(x, __shfl_xor(x, 4));  \
                     x = fmaxf(x, __shfl_xor(x, 2));  x = fmaxf(x, __shfl_xor(x, 1)); }

__device__ __forceinline__ ushort f2bf(float x) {
    uint u = __float_as_uint(x);
    u += 0x7FFF + ((u >> 16) & 1);
    return (ushort)(u >> 16);
}
__device__ __forceinline__ float bfs(ushort u) { return __uint_as_float(((uint)u) << 16); }
__device__ __forceinline__ float bflo(uint u) { return __uint_as_float(u << 16); }
__device__ __forceinline__ float bfhi(uint u) { return __uint_as_float(u & 0xFFFF0000u); }

// ===== k_front: emb 64-rows/block (0..512) | prep (513..517) | fragB (518) |
//                fragC (519..520) | hist (521..1544) =====
__global__ __launch_bounds__(256) void k_front(
    const float* __restrict__ node_feats, const float* __restrict__ We,
    const float* __restrict__ be,
    const float* __restrict__ a0, const float* __restrict__ a1, const float* __restrict__ a2,
    const float* __restrict__ W0, const float* __restrict__ W1, const float* __restrict__ W2,
    const float* __restrict__ b0, const float* __restrict__ b1, const float* __restrict__ b2,
    const float* __restrict__ Wd, const float* __restrict__ bd,
    const int* __restrict__ bscope) {
    int tid = threadIdx.x;
    if (blockIdx.x < 513) {
        __shared__ float Ws[576];
        __shared__ float As6[6][68];
        __shared__ float fsAll[576];
        __shared__ float hsAll[64][68];
        int r0 = blockIdx.x * 64;
        for (int i = tid; i < 576; i += 256) Ws[i] = We[i];
        for (int t = tid; t < 384; t += 256) {
            int vec = t >> 6, j = t & 63;
            const float* Av = (vec >> 1) == 0 ? a0 : ((vec >> 1) == 1 ? a1 : a2);
            As6[vec][j] = Av[((vec & 1) << 6) + j];
        }
        for (int t = tid; t < 576; t += 256) {
            int row = r0 + t / 9;
            float v = 0.f;
            if (row >= 1 && row <= NNODES) v = node_feats[(size_t)(row - 1) * 9 + (t % 9)];
            fsAll[t] = v;
        }
        __syncthreads();
        int j = tid & 63;
        float bj = be[j];
#pragma unroll 4
        for (int p = 0; p < 16; p++) {
            int lr = p * 4 + (tid >> 6);
            int row = r0 + lr;
            float acc = bj;
#pragma unroll
            for (int k = 0; k < 9; k++) acc += fsAll[lr * 9 + k] * Ws[k * 64 + j];
            float v = (row == 0 || row >= NSEG) ? 0.f : acc;
            if (row < NSEG) g_tfp[3 * PSZ + (size_t)row * 64 + j] = f2bf(v);
            hsAll[lr][j] = v;
        }
        __syncthreads();
#pragma unroll
        for (int i = 0; i < 12; i++) {
            int task = i * 256 + tid;
            int d = task >> 3, g = tid & 7;
            int lr = d / 6, vec = d % 6;
            float s = 0.f;
#pragma unroll
            for (int jj = 0; jj < 8; jj++)
                s += hsAll[lr][g * 8 + jj] * As6[vec][g * 8 + jj];
            s += __shfl_xor(s, 1); s += __shfl_xor(s, 2); s += __shfl_xor(s, 4);
            int prow = r0 + lr;
            if (g == 0 && prow < NSEG) {
                int iv = vec >> 1;
                if ((vec & 1) == 0) g_p0[iv][prow] = s;
                else                g_p1[iv][prow] = s;
            }
        }
    } else if (blockIdx.x < 518) {
        int pb = blockIdx.x - 513;
        int k = tid;
        if (pb < 3) {
            int it = pb;
            const float* W = it == 0 ? W0 : (it == 1 ? W1 : W2);
            const float* a = it == 0 ? a0 : (it == 1 ? a1 : a2);
            const float* bias = it == 0 ? b0 : (it == 1 ? b1 : b2);
            int d = 64 * (it + 1);
            if (k < d) {
                float s = 0.f;
                for (int jj = 0; jj < d; jj++) s += W[(size_t)k * d + jj] * a[128 + jj];
                g_w2[it][k] = s;
            } else if (k == 255) {
                float c = 0.f;
                for (int jj = 0; jj < d; jj++) c += a[128 + jj] * bias[jj];
                g_w2[it][255] = c;
            }
        } else if (pb == 3) {
            __shared__ float w2s[64];
            if (k < 64) {
                float s = 0.f;
                for (int jj = 0; jj < 64; jj++) s += W0[(size_t)k * 64 + jj] * a0[128 + jj];
                w2s[k] = s;
            }
            __syncthreads();
            if (k < 10) {
                float s = 0.f;
                for (int jj = 0; jj < 64; jj++) s += Wd[(size_t)k * 64 + jj] * w2s[jj];
                g_wq10[k] = s;
            } else if (k == 64) {
                float s = 0.f, c = 0.f;
                for (int jj = 0; jj < 64; jj++) { s += bd[jj] * w2s[jj]; c += a0[128 + jj] * b0[jj]; }
                g_cq = s + c;
            }
        } else {
            for (int t = k; t < 640; t += 256) {
                int kk = t >> 6, jj = t & 63;
                float s = 0.f;
                for (int m = 0; m < 64; m++) s += Wd[kk * 64 + m] * W0[(size_t)m * 64 + jj];
                g_wc[t] = s;
            }
            if (k < 64) {
                float s = b0[k];
                for (int m = 0; m < 64; m++) s += bd[m] * W0[(size_t)m * 64 + k];
                g_bcc[k] = s;
            }
        }
    } else if (blockIdx.x == 518) {
        for (int t = tid; t < 2048; t += 256) {
            int nt = t >> 8, ks = (t >> 6) & 3, l = t & 63;
            int n = nt * 16 + (l & 15);
            int kb = ks * 32 + ((l >> 4) << 3);
            ushort* dst = &g_wbB[(size_t)t * 8];
#pragma unroll
            for (int i = 0; i < 8; i++)
                dst[i] = f2bf(W1[(size_t)(kb + i) * 128 + n]);
        }
    } else if (blockIdx.x <= 520) {
        int half = blockIdx.x - 519;
        for (int t = tid; t < 2304; t += 256) {
            int nt = half * 6 + t / 384;
            int rem = t % 384;
            int ks = rem >> 6, l = rem & 63;
            int n = nt * 16 + (l & 15);
            int kb = ks * 32 + ((l >> 4) << 3);
            ushort* dst = &g_wbC[((size_t)(nt * 6 + ks) * 64 + l) * 8];
#pragma unroll
            for (int i = 0; i < 8; i++)
                dst[i] = f2bf(W2[(size_t)(kb + i) * 192 + n]);
        }
    } else {
        int e = (blockIdx.x - 521) * 256 + tid;
        if (e < NE) atomicAdd(&g_counts[bscope[e]], 1);
    }
}

// ---------------- scans ----------------
__global__ void k_scan1() {
    __shared__ int s[256];
    int t = threadIdx.x, i = blockIdx.x * 256 + t;
    int v = (i < NSEG) ? g_counts[i] : 0;
    s[t] = v; __syncthreads();
    for (int off = 1; off < 256; off <<= 1) {
        int tmp = (t >= off) ? s[t - off] : 0;
        __syncthreads();
        s[t] += tmp;
        __syncthreads();
    }
    if (i < NSEG) g_excl[i] = s[t] - v;
    if (t == 255) g_bsum[blockIdx.x] = s[255];
}

__global__ void k_scan2(int nb) {
    __shared__ int s[256];
    int t = threadIdx.x;
    int v = (t < nb) ? g_bsum[t] : 0;
    s[t] = v; __syncthreads();
    for (int off = 1; off < 256; off <<= 1) {
        int tmp = (t >= off) ? s[t - off] : 0;
        __syncthreads();
        s[t] += tmp;
        __syncthreads();
    }
    if (t < nb) g_bsum[t] = s[t] - v;   // exclusive
}

__global__ void k_scan3() {
    __shared__ int lh[128];
    int t = threadIdx.x;
    if (t < 128) lh[t] = 0;
    __syncthreads();
    int i = blockIdx.x * 256 + t;
    if (i < NSEG) {
        g_rowptr[i] = g_excl[i] + g_bsum[i >> 8];
        int cnt = g_counts[i];
        atomicAdd(&lh[cnt > 127 ? 127 : cnt], 1);
    }
    if (i == NSEG) g_rowptr[NSEG] = NE;
    __syncthreads();
    if (t < 128 && lh[t]) atomicAdd(&g_bc[t], lh[t]);
}

// ---- scatter + per-edge 64B record build (coalesced reads, L2-resident gathers) ----
__global__ __launch_bounds__(256) void k_scatter(const int* __restrict__ bs,
                                                 const float* __restrict__ fdg,
                                                 const float* __restrict__ rij,
                                                 const int* __restrict__ see,
                                                 const int* __restrict__ g1,
                                                 const int* __restrict__ g2) {
    __shared__ float wqs[10];
    if (threadIdx.x < 10) wqs[threadIdx.x] = g_wq10[threadIdx.x];
    __syncthreads();
    int e = blockIdx.x * 256 + threadIdx.x;
    if (e >= NE) return;
    int seg = bs[e];
    int pos = g_rowptr[seg] + atomicAdd(&g_cur[seg], 1);
    g_csr[pos] = e;
    float x[10];
#pragma unroll
    for (int k = 0; k < 9; k++) x[k] = fdg[(size_t)e * 9 + k];
    x[9] = rij[e];
    int s0 = see[2 * (size_t)e], s1 = see[2 * (size_t)e + 1];
    float q = g_cq;
#pragma unroll
    for (int k = 0; k < 10; k++) q += x[k] * wqs[k];
    float lb0 = q + g_p0[0][s0] + g_p1[0][s1];
    float pe1 = g_p0[1][s0] + g_p1[1][s1];
    float pe2 = g_p0[2][s0] + g_p1[2][s1];
    size_t rb = (size_t)e * 4;
    g_rec[rb + 0] = make_float4(x[0], x[1], x[2], x[3]);
    g_rec[rb + 1] = make_float4(x[4], x[5], x[6], x[7]);
    g_rec[rb + 2] = make_float4(x[8], x[9], lb0, 0.f);
    g_rec[rb + 3] = make_float4(pe1, pe2, __int_as_float(g1[e]), __int_as_float(g2[e]));
}

// ===== k_mid: bscatter (0..128, + counts/cur cleanup) | sortidx (129..1152) |
//              attend0 unsorted (1153..9345) =====
__global__ __launch_bounds__(256) void k_mid() {
    int tid = threadIdx.x;
    if (blockIdx.x < 129) {
        __shared__ int sc[128];
        __shared__ int lh[128];
        __shared__ int lbase[128];
        if (tid < 128) { sc[tid] = g_bc[tid]; lh[tid] = 0; }
        __syncthreads();
        for (int off = 1; off < 128; off <<= 1) {
            int tmp = (tid >= off && tid < 128) ? sc[tid - off] : 0;
            __syncthreads();
            if (tid < 128) sc[tid] += tmp;
            __syncthreads();
        }
        int seg = blockIdx.x * 256 + tid;
        int bin = 0, lpos = 0;
        bool valid = seg < NSEG;
        if (valid) {
            int cnt = g_rowptr[seg + 1] - g_rowptr[seg];
            bin = cnt > 127 ? 127 : cnt;
            lpos = atomicAdd(&lh[bin], 1);
        }
        __syncthreads();
        if (tid < 128 && lh[tid] > 0)
            lbase[tid] = atomicAdd(&g_bcur[tid], lh[tid]);
        __syncthreads();
        if (valid) {
            int bstart = sc[bin] - g_bc[bin];
            g_sorder[bstart + lbase[bin] + lpos] = seg;
            g_counts[seg] = 0;
            g_cur[seg] = 0;
        }
    } else if (blockIdx.x < 1153) {
        int pos = (blockIdx.x - 129) * 256 + tid;
        if (pos >= NE) return;
        int e = g_csr[pos];
        f4 d = g_rec[(size_t)e * 4 + 3];
        g_pe1[pos] = d.x;
        g_pe2[pos] = d.y;
        g_g1s[pos] = __float_as_int(d.z);
        g_g2s[pos] = __float_as_int(d.w);
    } else {
        // ---- attend0 (unsorted): rec-based, softmax + out0 = elu(y@Wc+bcc) ----
        __shared__ float Wcs[640];
        __shared__ float bcs[64];
        for (int i = tid; i < 640; i += 256) Wcs[i] = g_wc[i];
        if (tid < 64) bcs[tid] = g_bcc[tid];
        __syncthreads();
        int lane = tid & 63;
        int seg = (blockIdx.x - 1153) * 4 + (tid >> 6);
        if (seg >= NSEG) return;
        int beg = g_rowptr[seg], end = g_rowptr[seg + 1];
        int cnt = end - beg;
        float y[10];
#pragma unroll
        for (int k = 0; k < 10; k++) y[k] = 0.f;

        if (cnt > 0 && cnt <= 64) {
            float l = -1e30f;
            float x[10];
#pragma unroll
            for (int k = 0; k < 10; k++) x[k] = 0.f;
            if (lane < cnt) {
                int e = g_csr[beg + lane];
                size_t rb = (size_t)e * 4;
                f4 r0 = g_rec[rb + 0];
                f4 r1 = g_rec[rb + 1];
                f4 r2 = g_rec[rb + 2];
                x[0] = r0.x; x[1] = r0.y; x[2] = r0.z; x[3] = r0.w;
                x[4] = r1.x; x[5] = r1.y; x[6] = r1.z; x[7] = r1.w;
                x[8] = r2.x; x[9] = r2.y;
                l = r2.z;
                l = l > 0.f ? l : 0.2f * l;
            }
            float m = l;
            WREDMAX(m);
            float ex = (lane < cnt) ? __expf(l - m) : 0.f;
            float den = ex;
            WREDUCE(den);
            float w = ex / den;
#pragma unroll
            for (int k = 0; k < 10; k++) {
                float s = w * x[k];
                WREDUCE(s);
                y[k] = s;
            }
        } else if (cnt > 64) {
            float m = -1e30f;
            for (int t = beg + lane; t < end; t += 64) {
                int e = g_csr[t];
                float l = g_rec[(size_t)e * 4 + 2].z;
                l = l > 0.f ? l : 0.2f * l;
                m = fmaxf(m, l);
            }
            WREDMAX(m);
            float den = 0.f;
            for (int t = beg + lane; t < end; t += 64) {
                int e = g_csr[t];
                float l = g_rec[(size_t)e * 4 + 2].z;
                l = l > 0.f ? l : 0.2f * l;
                den += __expf(l - m);
            }
            WREDUCE(den);
            float rden = 1.f / den;
            float part[10];
#pragma unroll
            for (int k = 0; k < 10; k++) part[k] = 0.f;
            for (int t = beg + lane; t < end; t += 64) {
                int e = g_csr[t];
                size_t rb = (size_t)e * 4;
                f4 r0 = g_rec[rb + 0];
                f4 r1 = g_rec[rb + 1];
                f4 r2 = g_rec[rb + 2];
                float l = r2.z;
                l = l > 0.f ? l : 0.2f * l;
                float w = __expf(l - m) * rden;
                part[0] += w * r0.x; part[1] += w * r0.y; part[2] += w * r0.z; part[3] += w * r0.w;
                part[4] += w * r1.x; part[5] += w * r1.y; part[6] += w * r1.z; part[7] += w * r1.w;
                part[8] += w * r2.x; part[9] += w * r2.y;
            }
#pragma unroll
            for (int k = 0; k < 10; k++) {
                WREDUCE(part[k]);
                y[k] = part[k];
            }
        }
        float o = bcs[lane];
#pragma unroll
        for (int k = 0; k < 10; k++) o += y[k] * Wcs[k * 64 + lane];
        if (cnt == 0) o = 0.f;
        o = o > 0.f ? o : (__expf(o) - 1.f);
        ushort h = g_tfp[3 * PSZ + (size_t)seg * 64 + lane];
        g_pkA[(size_t)seg * 64 + lane] = (uint)f2bf(o) | ((uint)h << 16);
        float qp = o * g_w2[1][lane] + bfs(h) * g_w2[1][64 + lane];
        WREDUCE(qp);
        if (lane == 0) g_q[seg] = qp + g_w2[1][255];
    }
}

// -------- attend iters 1/2: sorted index arrays, packed gathers --------
template <int NCM>
__global__ __launch_bounds__(256) void k_attendG() {
    const float* __restrict__ pe = (NCM == 2) ? g_pe1 : g_pe2;
    int lane = threadIdx.x & 63;
    int sidx = blockIdx.x * 4 + (threadIdx.x >> 6);
    if (sidx >= NSEG) return;
    int seg = g_sorder[sidx];
    int beg = g_rowptr[seg], end = g_rowptr[seg + 1];
    int cnt = end - beg;
    float acc[NCM];
#pragma unroll
    for (int c = 0; c < NCM; c++) acc[c] = 0.f;

    if (cnt > 0 && cnt <= 64) {
        float l = -1e30f;
        int i1 = 0, i2 = 0;
        if (lane < cnt) {
            i1 = g_g1s[beg + lane]; i2 = g_g2s[beg + lane];
            l = 0.5f * (g_q[i1] + g_q[i2]) + pe[beg + lane];
            l = l > 0.f ? l : 0.2f * l;
        }
        float m = l;
        WREDMAX(m);
        float ex = (lane < cnt) ? __expf(l - m) : 0.f;
        float den = ex;
        WREDUCE(den);
        float w = ex / den;
        for (int t0 = 0; t0 < cnt; t0 += 8) {
            float wt[8]; int a1[8], a2[8];
#pragma unroll
            for (int u = 0; u < 8; u++) {
                int su = t0 + u; su = su > 63 ? 63 : su;
                wt[u] = __shfl(w, su);
                a1[u] = __shfl(i1, su);
                a2[u] = __shfl(i2, su);
            }
            if (NCM == 2) {
                uint ua[8], ub[8];
#pragma unroll
                for (int u = 0; u < 8; u++) {
                    ua[u] = g_pkA[(size_t)a1[u] * 64 + lane];
                    ub[u] = g_pkA[(size_t)a2[u] * 64 + lane];
                }
#pragma unroll
                for (int u = 0; u < 8; u++) {
                    float wh = 0.5f * wt[u];
                    acc[0] += wh * (bflo(ua[u]) + bflo(ub[u]));
                    acc[1] += wh * (bfhi(ua[u]) + bfhi(ub[u]));
                }
            } else {
                uint ua[8], ub[8];
                ushort ha[8], hb[8];
#pragma unroll
                for (int u = 0; u < 8; u++) {
                    size_t b1 = (size_t)a1[u] * 64 + lane, b2 = (size_t)a2[u] * 64 + lane;
                    ua[u] = g_pk01[b1]; ub[u] = g_pk01[b2];
                    ha[u] = g_tfp[3 * PSZ + b1]; hb[u] = g_tfp[3 * PSZ + b2];
                }
#pragma unroll
                for (int u = 0; u < 8; u++) {
                    float wh = 0.5f * wt[u];
                    acc[0] += wh * (bflo(ua[u]) + bflo(ub[u]));
                    acc[1] += wh * (bfhi(ua[u]) + bfhi(ub[u]));
                    acc[2] += wh * (bfs(ha[u]) + bfs(hb[u]));
                }
            }
        }
    } else if (cnt > 64) {
        float m = -1e30f;
        for (int t = beg + lane; t < end; t += 64) {
            float l = 0.5f * (g_q[g_g1s[t]] + g_q[g_g2s[t]]) + pe[t];
            l = l > 0.f ? l : 0.2f * l;
            m = fmaxf(m, l);
        }
        WREDMAX(m);
        float den = 0.f;
        for (int t = beg + lane; t < end; t += 64) {
            float l = 0.5f * (g_q[g_g1s[t]] + g_q[g_g2s[t]]) + pe[t];
            l = l > 0.f ? l : 0.2f * l;
            den += __expf(l - m);
        }
        WREDUCE(den);
        float rden = 1.f / den;
        for (int t = beg; t < end; t++) {
            float l = 0.5f * (g_q[g_g1s[t]] + g_q[g_g2s[t]]) + pe[t];
            l = l > 0.f ? l : 0.2f * l;
            float w = __expf(l - m) * rden;
            float wh = 0.5f * w;
            size_t b1 = (size_t)g_g1s[t] * 64 + lane, b2 = (size_t)g_g2s[t] * 64 + lane;
            if (NCM == 3) {
                uint ua = g_pk01[b1], ub = g_pk01[b2];
                acc[0] += wh * (bflo(ua) + bflo(ub));
                acc[1] += wh * (bfhi(ua) + bfhi(ub));
                acc[2] += wh * (bfs(g_tfp[3 * PSZ + b1]) + bfs(g_tfp[3 * PSZ + b2]));
            } else {
                uint ua = g_pkA[b1], ub = g_pkA[b2];
                acc[0] += wh * (bflo(ua) + bflo(ub));
                acc[1] += wh * (bfhi(ua) + bfhi(ub));
            }
        }
    }
#pragma unroll
    for (int c = 0; c < NCM; c++)
        g_msumh[(size_t)seg * 192 + lane + 64 * c] = f2bf(acc[c]);
}

// ----- iter1 GEMM (MFMA): 64 rows/block, 4 waves x (16 rows x 128 cols); K=128 -----
__global__ __launch_bounds__(256) void k_gemmB(const float* __restrict__ bias) {
    int tid = threadIdx.x;
    if (blockIdx.x == 0 && tid < 128) { g_bc[tid] = 0; g_bcur[tid] = 0; }
    int w = tid >> 6, l = tid & 63;
    int lm = l & 15, lk = l >> 4;
    int r0 = blockIdx.x * 64 + w * 16;
    int arow = r0 + lm;
    size_t abase = (size_t)(arow < NSEG ? arow : 0) * 192;
    f32x4 acc[8];
#pragma unroll
    for (int nt = 0; nt < 8; nt++) acc[nt] = (f32x4){0.f, 0.f, 0.f, 0.f};
#pragma unroll
    for (int ks = 0; ks < 4; ks++) {
        bf16x8 af = *(const bf16x8*)&g_msumh[abase + ks * 32 + lk * 8];
#pragma unroll
        for (int nt = 0; nt < 8; nt++) {
            bf16x8 bf = *(const bf16x8*)&g_wbB[((size_t)(nt * 4 + ks) * 64 + l) * 8];
            acc[nt] = __builtin_amdgcn_mfma_f32_16x16x32_bf16(af, bf, acc[nt], 0, 0, 0);
        }
    }
#pragma unroll
    for (int j = 0; j < 4; j++) {
        int row = r0 + lk * 4 + j;
        bool valid = row < NSEG;
        int rr = valid ? row : 0;
        bool nonempty = valid && (g_rowptr[row + 1] > g_rowptr[row]);
        float qp = 0.f;
#pragma unroll
        for (int nt = 0; nt < 4; nt++) {
            int c = nt * 16 + lm;
            float vl = acc[nt][j] + bias[c];
            float vh = acc[nt + 4][j] + bias[64 + c];
            if (!nonempty) { vl = 0.f; vh = 0.f; }
            vl = vl > 0.f ? vl : (__expf(vl) - 1.f);
            vh = vh > 0.f ? vh : (__expf(vh) - 1.f);
            float hc = bfs(g_tfp[3 * PSZ + (size_t)rr * 64 + c]);
            if (valid) g_pk01[(size_t)row * 64 + c] = (uint)f2bf(vl) | ((uint)f2bf(vh) << 16);
            qp += vl * g_w2[2][c] + vh * g_w2[2][64 + c] + hc * g_w2[2][128 + c];
        }
        qp += __shfl_xor(qp, 1); qp += __shfl_xor(qp, 2);
        qp += __shfl_xor(qp, 4); qp += __shfl_xor(qp, 8);
        if (valid && lm == 0) g_q[row] = qp + g_w2[2][255];
    }
}

// ----- iter2 GEMM (MFMA): 64 rows/block, 4 waves x (16 rows x 192 cols); K=192 -----
__global__ __launch_bounds__(256) void k_gemmC(const float* __restrict__ bias) {
    int tid = threadIdx.x;
    int w = tid >> 6, l = tid & 63;
    int lm = l & 15, lk = l >> 4;
    int r0 = blockIdx.x * 64 + w * 16;
    int arow = r0 + lm;
    size_t abase = (size_t)(arow < NSEG ? arow : 0) * 192;
    f32x4 acc[12];
#pragma unroll
    for (int nt = 0; nt < 12; nt++) acc[nt] = (f32x4){0.f, 0.f, 0.f, 0.f};
#pragma unroll
    for (int ks = 0; ks < 6; ks++) {
        bf16x8 af = *(const bf16x8*)&g_msumh[abase + ks * 32 + lk * 8];
#pragma unroll
        for (int nt = 0; nt < 12; nt++) {
            bf16x8 bf = *(const bf16x8*)&g_wbC[((size_t)(nt * 6 + ks) * 64 + l) * 8];
            acc[nt] = __builtin_amdgcn_mfma_f32_16x16x32_bf16(af, bf, acc[nt], 0, 0, 0);
        }
    }
#pragma unroll
    for (int j = 0; j < 4; j++) {
        int row = r0 + lk * 4 + j;
        if (row >= NSEG) continue;
        bool nonempty = g_rowptr[row + 1] > g_rowptr[row];
#pragma unroll
        for (int nt = 0; nt < 12; nt++) {
            int col = nt * 16 + lm;
            float v = acc[nt][j] + bias[col];
            if (!nonempty) v = 0.f;
            v = v > 0.f ? v : (__expf(v) - 1.f);
            int plane = nt >> 2, c = col & 63;
            g_tfp[(size_t)plane * PSZ + (size_t)row * 64 + c] = f2bf(v);
        }
    }
}

// ---------------- final: per-molecule gather-sum ----------------
__global__ void k_final(const int* __restrict__ lscope, float* __restrict__ out) {
    __shared__ int idx[32];
    __shared__ float sm[4][256];
    int m = blockIdx.x, tid = threadIdx.x, w = tid >> 6, lane = tid & 63;
    if (tid < 32) idx[tid] = lscope[m * 32 + tid];
    __syncthreads();
    float a0 = 0.f, a1 = 0.f, a2 = 0.f, a3 = 0.f;
#pragma unroll
    for (int j = w * 8; j < w * 8 + 8; j++) {
        size_t base = (size_t)idx[j] * 64 + lane;
        a0 += bfs(g_tfp[base]);
        a1 += bfs(g_tfp[PSZ + base]);
        a2 += bfs(g_tfp[2 * PSZ + base]);
        a3 += bfs(g_tfp[3 * PSZ + base]);
    }
    sm[w][lane] = a0; sm[w][64 + lane] = a1; sm[w][128 + lane] = a2; sm[w][192 + lane] = a3;
    __syncthreads();
    out[(size_t)m * 256 + tid] = sm[0][tid] + sm[1][tid] + sm[2][tid] + sm[3][tid];
}

extern "C" void kernel_launch(void* const* d_in, const int* in_sizes, int n_in,
                              void* d_out, int out_size, void* d_ws, size_t ws_size,
                              hipStream_t stream) {
    const float* node_feats = (const float*)d_in[0];
    const float* fdg        = (const float*)d_in[1];
    const float* rij        = (const float*)d_in[2];
    const int*   see        = (const int*)d_in[3];
    const int*   b_scope    = (const int*)d_in[4];
    const int*   scope_up   = (const int*)d_in[5];
    const int*   scope_lig  = (const int*)d_in[6];
    const int*   l_scope    = (const int*)d_in[7];
    const float* W_emb      = (const float*)d_in[8];
    const float* b_emb      = (const float*)d_in[9];
    const float* W_dist     = (const float*)d_in[10];
    const float* b_dist     = (const float*)d_in[11];
    const float* fc_W[3]   = {(const float*)d_in[12], (const float*)d_in[15], (const float*)d_in[18]};
    const float* fc_b[3]   = {(const float*)d_in[13], (const float*)d_in[16], (const float*)d_in[19]};
    const float* attn_a[3] = {(const float*)d_in[14], (const float*)d_in[17], (const float*)d_in[20]};

    k_front<<<1545, 256, 0, stream>>>(node_feats, W_emb, b_emb,
                                      attn_a[0], attn_a[1], attn_a[2],
                                      fc_W[0], fc_W[1], fc_W[2],
                                      fc_b[0], fc_b[1], fc_b[2],
                                      W_dist, b_dist, b_scope);
    k_scan1<<<129, 256, 0, stream>>>();
    k_scan2<<<1, 256, 0, stream>>>(129);
    k_scan3<<<129, 256, 0, stream>>>();
    k_scatter<<<NE / 256, 256, 0, stream>>>(b_scope, fdg, rij, see, scope_lig, scope_up);
    k_mid<<<9346, 256, 0, stream>>>();

    // iter 1
    k_attendG<2><<<8193, 256, 0, stream>>>();
    k_gemmB<<<513, 256, 0, stream>>>(fc_b[1]);
    // iter 2
    k_attendG<3><<<8193, 256, 0, stream>>>();
    k_gemmC<<<513, 256, 0, stream>>>(fc_b[2]);

    k_final<<<2048, 256, 0, stream>>>(l_scope, (float*)d_out);
}